// Round 5
// baseline (3284.360 us; speedup 1.0000x reference)
//
#include <hip/hip_runtime.h>
#include <hip/hip_bf16.h>
#include <math.h>

// ---------- helpers ----------
__device__ __forceinline__ float siluf(float x) {
    float e = __expf(-fabsf(x));
    float s = (x >= 0.f) ? 1.f / (1.f + e) : e / (1.f + e);
    return x * s;
}
__device__ __forceinline__ float softplusf(float x) {
    if (x > 20.f) return x;
    if (x < -20.f) return __expf(x);
    return log1pf(__expf(x));
}

// ---------- generic 64x64 tiled GEMM (fp32) ----------
// C[M,N] = A[M,K] * B[K,N]
// ACOL: A element (m,k) at A[k*lda + m]
// BCOL: B element (k,n) at B[n*ldb + k]
// AMUL: A_eff = A1 * silu(A2) (row-major)
// EPI==1: C = softplus(C + bias[n])
// blockIdx.z = batch (batA/batB/batC element offsets)
template<bool ACOL, bool BCOL, bool AMUL, int EPI>
__global__ __launch_bounds__(256) void gemm64(
    const float* __restrict__ A, const float* __restrict__ Bw, float* __restrict__ C,
    const float* __restrict__ A2, const float* __restrict__ bias,
    int M, int N, int K, int lda, int ldb, int ldc, int lda2,
    long batA, long batB, long batC)
{
    __shared__ __align__(16) float As[16][64];
    __shared__ __align__(16) float Bs[16][64];
    int tx = threadIdx.x;
    int m0 = blockIdx.x * 64, n0 = blockIdx.y * 64;
    A += blockIdx.z * batA; Bw += blockIdx.z * batB; C += blockIdx.z * batC;
    int tm = tx >> 4, tn = tx & 15;
    float acc[4][4] = {};
    for (int k0 = 0; k0 < K; k0 += 16) {
        for (int i = tx; i < 1024; i += 256) {
            int mm, kk;
            if (ACOL) { mm = i & 63; kk = i >> 6; } else { kk = i & 15; mm = i >> 4; }
            int m = m0 + mm, k = k0 + kk;
            float v = 0.f;
            if (m < M && k < K) {
                long ia = ACOL ? ((long)k * lda + m) : ((long)m * lda + k);
                v = A[ia];
                if (AMUL) v *= siluf(A2[(long)m * lda2 + k]);
            }
            As[kk][mm] = v;
        }
        for (int i = tx; i < 1024; i += 256) {
            int nn, kk;
            if (BCOL) { kk = i & 15; nn = i >> 4; } else { nn = i & 63; kk = i >> 6; }
            int n = n0 + nn, k = k0 + kk;
            float v = 0.f;
            if (n < N && k < K) {
                long ib = BCOL ? ((long)n * ldb + k) : ((long)k * ldb + n);
                v = Bw[ib];
            }
            Bs[kk][nn] = v;
        }
        __syncthreads();
#pragma unroll
        for (int kk = 0; kk < 16; ++kk) {
            float4 av = *(const float4*)&As[kk][tm * 4];
            float4 bv = *(const float4*)&Bs[kk][tn * 4];
            float a[4] = {av.x, av.y, av.z, av.w};
            float b[4] = {bv.x, bv.y, bv.z, bv.w};
#pragma unroll
            for (int i = 0; i < 4; i++)
#pragma unroll
                for (int j = 0; j < 4; j++) acc[i][j] += a[i] * b[j];
        }
        __syncthreads();
    }
#pragma unroll
    for (int i = 0; i < 4; i++) {
        int m = m0 + tm * 4 + i;
        if (m >= M) continue;
#pragma unroll
        for (int j = 0; j < 4; j++) {
            int n = n0 + tn * 4 + j;
            if (n >= N) continue;
            float v = acc[i][j];
            if (EPI == 1) v = softplusf(v + bias[n]);
            C[(long)m * ldc + n] = v;
        }
    }
}

// ---------- causal depthwise conv (k=4) + bias + silu ----------
__global__ void conv_silu_kernel(const float* __restrict__ xz, const float* __restrict__ w,
                                 const float* __restrict__ bias, float* __restrict__ out,
                                 int Bn, int L, int din, int ldx)
{
    int idx = blockIdx.x * 256 + threadIdx.x;
    int total = Bn * L * din;
    if (idx >= total) return;
    int c = idx % din;
    int r = idx / din;
    int t = r % L;
    int b = r / L;
    float acc = bias[c];
#pragma unroll
    for (int i = 0; i < 4; i++) {
        int tt = t - 3 + i;
        if (tt >= 0) acc += w[c * 4 + i] * xz[((long)(b * L + tt)) * ldx + c];
    }
    out[idx] = siluf(acc);
}

// ---------- selective scan ----------
// 256 thr = 16 d-lanes x 16 n-lanes; blockIdx.x = d-block, blockIdx.y = b
// u/y may alias (no __restrict__; each chunk fully read into LDS + barrier before stores)
template<int T>
__global__ __launch_bounds__(256) void scan_kernel(
    const float* u, const float* dt,
    const float* xdbl, const float* __restrict__ A_log,
    const float* __restrict__ Dp, float* y,
    int din, int L, int xld, int boff, int coff)
{
    __shared__ float Bc[T][16], Cc[T][16], dtc[T][16], uc[T][16], yc[T][16];
    int tx = threadIdx.x;
    int dl = tx >> 4;
    int n = tx & 15;
    int dbase = blockIdx.x * 16;
    int dg = dbase + dl;
    int b = blockIdx.y;
    bool act = dg < din;
    float Acoef = act ? -__expf(A_log[dg * 16 + n]) : 0.f;
    float Dv = act ? Dp[dg] : 0.f;
    int nvalid = min(16, din - dbase);
    float h = 0.f;
    for (int c0 = 0; c0 < L; c0 += T) {
        int tcnt = min(T, L - c0);
        for (int i = tx; i < T * 16; i += 256) {
            int tt = i >> 4, c = i & 15;
            if (tt < tcnt) {
                long row = (long)b * L + c0 + tt;
                float uv = 0.f, dv = 0.f;
                if (c < nvalid) { uv = u[row * din + dbase + c]; dv = dt[row * din + dbase + c]; }
                uc[tt][c] = uv; dtc[tt][c] = dv;
                Bc[tt][c] = xdbl[row * xld + boff + c];
                Cc[tt][c] = xdbl[row * xld + coff + c];
            }
        }
        __syncthreads();
        for (int tt = 0; tt < tcnt; ++tt) {
            float dtv = dtc[tt][dl];
            float uv = uc[tt][dl];
            float dA = __expf(dtv * Acoef);
            h = dA * h + (dtv * uv) * Bc[tt][n];
            float p = h * Cc[tt][n];
            p += __shfl_xor(p, 1);
            p += __shfl_xor(p, 2);
            p += __shfl_xor(p, 4);
            p += __shfl_xor(p, 8);
            if (n == 0) yc[tt][dl] = p + Dv * uv;
        }
        __syncthreads();
        for (int i = tx; i < tcnt * 16; i += 256) {
            int tt = i >> 4, c = i & 15;
            if (c < nvalid) y[((long)b * L + c0 + tt) * din + dbase + c] = yc[tt][c];
        }
        __syncthreads();
    }
}

// ---------- mean over n (98) + softmax over k (1024), per batch ----------
__global__ void mean_softmax_kernel(const float* __restrict__ sc2, float* __restrict__ s)
{
    __shared__ float vals[1024];
    __shared__ float red[256];
    int b = blockIdx.x, tx = threadIdx.x;
    for (int k = tx; k < 1024; k += 256) {
        const float* row = sc2 + ((long)b * 1024 + k) * 98;
        float sum = 0.f;
        for (int nn = 0; nn < 98; nn++) sum += row[nn];
        vals[k] = sum * (1.f / 98.f);
    }
    __syncthreads();
    float mx = -1e30f;
    for (int k = tx; k < 1024; k += 256) mx = fmaxf(mx, vals[k]);
    red[tx] = mx; __syncthreads();
    for (int st = 128; st > 0; st >>= 1) { if (tx < st) red[tx] = fmaxf(red[tx], red[tx + st]); __syncthreads(); }
    mx = red[0]; __syncthreads();
    float lsum = 0.f;
    for (int k = tx; k < 1024; k += 256) { float e = __expf(vals[k] - mx); vals[k] = e; lsum += e; }
    red[tx] = lsum; __syncthreads();
    for (int st = 128; st > 0; st >>= 1) { if (tx < st) red[tx] += red[tx + st]; __syncthreads(); }
    float inv = 1.f / red[0];
    __syncthreads();
    for (int k = tx; k < 1024; k += 256) s[(long)b * 1024 + k] = vals[k] * inv;
}

// ---------- top-98 by 98 sequential max-reductions (jax semantics exactly) ----------
// key = (orderable(value)<<32) | ~index ; max key = largest value, ties -> lowest index.
__global__ __launch_bounds__(256) void topk_select_kernel(const float* __restrict__ s,
                                                          int* __restrict__ ind,
                                                          float* __restrict__ vtopk)
{
    __shared__ unsigned long long arr[1024];
    __shared__ unsigned long long red[256];
    int b = blockIdx.x, tx = threadIdx.x;
    for (int k = tx; k < 1024; k += 256) {
        float v = s[b * 1024 + k];
        unsigned u = __float_as_uint(v);
        u = (u & 0x80000000u) ? ~u : (u | 0x80000000u);
        arr[k] = ((unsigned long long)u << 32) | (unsigned)(~k);
    }
    __syncthreads();
    for (int r = 0; r < 98; ++r) {
        unsigned long long m = 0ull;
        for (int k = tx; k < 1024; k += 256) m = (arr[k] > m) ? arr[k] : m;
        red[tx] = m; __syncthreads();
        for (int st = 128; st > 0; st >>= 1) {
            if (tx < st && red[tx + st] > red[tx]) red[tx] = red[tx + st];
            __syncthreads();
        }
        unsigned long long best = red[0];
        if (tx == 0) {
            unsigned lo = (unsigned)(best & 0xffffffffu);
            int kidx = (int)(~lo);
            unsigned ub = (unsigned)(best >> 32);
            unsigned fb = (ub & 0x80000000u) ? (ub ^ 0x80000000u) : ~ub;
            ind[b * 98 + r] = kidx;
            vtopk[b * 98 + r] = __uint_as_float(fb);
            arr[kidx] = 0ull;   // remove from future rounds
        }
        __syncthreads();
    }
}

// ---------- gather: h[b,j,:] = img[j,:] + kf[b,:,ind]*v ----------
__global__ void gather_kernel(const float* __restrict__ img, const float* __restrict__ kf,
                              const int* __restrict__ ind, const float* __restrict__ vtopk,
                              float* __restrict__ h)
{
    int j = blockIdx.x, b = blockIdx.y;
    int kidx = ind[b * 98 + j];
    float v = vtopk[b * 98 + j];
    long hbase = ((long)b * 98 + j) * 2048;
    const float* kfb = kf + (long)b * 2048 * 1024 + kidx;
    for (int d = threadIdx.x; d < 2048; d += 256)
        h[hbase + d] = img[(long)j * 2048 + d] + kfb[(long)d * 1024] * v;
}

// ---------- host launch ----------
extern "C" void kernel_launch(void* const* d_in, const int* in_sizes, int n_in,
                              void* d_out, int out_size, void* d_ws, size_t ws_size,
                              hipStream_t stream)
{
    const float* imgF      = (const float*)d_in[0];
    const float* kf        = (const float*)d_in[1];
    const float* a_in_w    = (const float*)d_in[2];
    const float* a_conv_w  = (const float*)d_in[3];
    const float* a_conv_b  = (const float*)d_in[4];
    const float* a_xproj_w = (const float*)d_in[5];
    const float* a_dt_w    = (const float*)d_in[6];
    const float* a_dt_b    = (const float*)d_in[7];
    const float* a_A_log   = (const float*)d_in[8];
    const float* a_D       = (const float*)d_in[9];
    const float* a_out_w   = (const float*)d_in[10];
    const float* c_in_w    = (const float*)d_in[11];
    const float* c_conv_w  = (const float*)d_in[12];
    const float* c_conv_b  = (const float*)d_in[13];
    const float* c_xproj_w = (const float*)d_in[14];
    const float* c_dt_w    = (const float*)d_in[15];
    const float* c_dt_b    = (const float*)d_in[16];
    const float* c_A_log   = (const float*)d_in[17];
    const float* c_D       = (const float*)d_in[18];
    const float* c_out_w   = (const float*)d_in[19];

    float* fout = (float*)d_out;   // reference output dtype is float32 -> float*

    float* ws = (float*)d_ws;
    float* h_buf  = ws;                      // 1,605,632 floats
    float* S      = ws + 1605632;
    // stage A
    float* score  = S;                       // 802,816 (reused as score2)
    float* xz_a   = S + 802816;              // 3,211,264
    float* xi_a   = S + 4014080;             // 1,605,632 (scan u AND y, in-place)
    float* xdbl_a = S + 5619712;             // 319,488
    float* dt_a   = S + 5939200;             // 1,605,632
    float* sbuf   = S + 7544832;             // 8,192
    int*   indb   = (int*)(S + 7553024);     // 784
    float* vtopk  = S + 7553808;             // 784
    // stage C (aliases stage A region; all stage-A data dead by then)
    float* xz_c   = S;                       // 6,422,528
    float* xi_c   = S + 6422528;             // 3,211,264 (scan u AND y, in-place)
    float* xdbl_c = S + 9633792;             // 125,440
    float* dt_c   = S + 9759232;             // 3,211,264
    // total ws: 14,576,128 floats = 58.3 MB

    // 1. score[b,k,n] = sum_d kf[b,d,k]*img[n,d]
    gemm64<true, true, false, 0><<<dim3(16, 2, 8), 256, 0, stream>>>(
        kf, imgF, score, nullptr, nullptr,
        1024, 98, 2048, 1024, 2048, 98, 0,
        (long)2048 * 1024, 0L, (long)1024 * 98);

    // 2. xz_a = score @ a_in_w
    gemm64<false, false, false, 0><<<dim3(128, 7, 1), 256, 0, stream>>>(
        score, a_in_w, xz_a, nullptr, nullptr, 8192, 392, 98, 98, 392, 392, 0, 0L, 0L, 0L);

    // 3. conv + silu -> xi_a
    conv_silu_kernel<<<6272, 256, 0, stream>>>(xz_a, a_conv_w, a_conv_b, xi_a, 8, 1024, 196, 392);

    // 4. xdbl_a = xi_a @ a_xproj_w
    gemm64<false, false, false, 0><<<dim3(128, 1, 1), 256, 0, stream>>>(
        xi_a, a_xproj_w, xdbl_a, nullptr, nullptr, 8192, 39, 196, 196, 39, 39, 0, 0L, 0L, 0L);

    // 5. dt_a = softplus(xdbl_a[:, :7] @ a_dt_w + a_dt_b)
    gemm64<false, false, false, 1><<<dim3(128, 4, 1), 256, 0, stream>>>(
        xdbl_a, a_dt_w, dt_a, nullptr, a_dt_b, 8192, 196, 7, 39, 196, 196, 0, 0L, 0L, 0L);

    // 6. selective scan A (in-place y over u)
    scan_kernel<64><<<dim3(13, 8, 1), 256, 0, stream>>>(
        xi_a, dt_a, xdbl_a, a_A_log, a_D, xi_a, 196, 1024, 39, 7, 23);

    // 7. score2 = (ya * silu(z_a)) @ a_out_w
    gemm64<false, false, true, 0><<<dim3(128, 2, 1), 256, 0, stream>>>(
        xi_a, a_out_w, score, xz_a + 196, nullptr, 8192, 98, 196, 196, 98, 98, 392, 0L, 0L, 0L);

    // 8. mean over n + softmax over k
    mean_softmax_kernel<<<8, 256, 0, stream>>>(score, sbuf);

    // 9. top-98 (sequential selection, jax tie semantics)
    topk_select_kernel<<<8, 256, 0, stream>>>(sbuf, indb, vtopk);

    // 10. h = img + kf_t[ind]*vtopk
    gather_kernel<<<dim3(98, 8, 1), 256, 0, stream>>>(imgF, kf, indb, vtopk, h_buf);

    // 11. xz_c = h @ c_in_w
    gemm64<false, false, false, 0><<<dim3(13, 128, 1), 256, 0, stream>>>(
        h_buf, c_in_w, xz_c, nullptr, nullptr, 784, 8192, 2048, 2048, 8192, 8192, 0, 0L, 0L, 0L);

    // 12. conv + silu -> xi_c
    conv_silu_kernel<<<12544, 256, 0, stream>>>(xz_c, c_conv_w, c_conv_b, xi_c, 8, 98, 4096, 8192);

    // 13. xdbl_c = xi_c @ c_xproj_w
    gemm64<false, false, false, 0><<<dim3(13, 3, 1), 256, 0, stream>>>(
        xi_c, c_xproj_w, xdbl_c, nullptr, nullptr, 784, 160, 4096, 4096, 160, 160, 0, 0L, 0L, 0L);

    // 14. dt_c = softplus(xdbl_c[:, :128] @ c_dt_w + c_dt_b)
    gemm64<false, false, false, 1><<<dim3(13, 64, 1), 256, 0, stream>>>(
        xdbl_c, c_dt_w, dt_c, nullptr, c_dt_b, 784, 4096, 128, 160, 4096, 4096, 0, 0L, 0L, 0L);

    // 15. selective scan C (in-place y over u)
    scan_kernel<98><<<dim3(256, 8, 1), 256, 0, stream>>>(
        xi_c, dt_c, xdbl_c, c_A_log, c_D, xi_c, 4096, 98, 160, 128, 144);

    // 16. out = (y_c * silu(z_c)) @ c_out_w  -> written DIRECTLY to d_out as fp32
    gemm64<false, false, true, 0><<<dim3(13, 32, 1), 256, 0, stream>>>(
        xi_c, c_out_w, fout, xz_c + 4096, nullptr, 784, 2048, 4096, 4096, 2048, 2048, 8192, 0L, 0L, 0L);
}

// Round 6
// 2077.195 us; speedup vs baseline: 1.5812x; 1.5812x over previous
//
#include <hip/hip_runtime.h>
#include <hip/hip_bf16.h>
#include <math.h>

typedef __attribute__((ext_vector_type(8))) short short8;
typedef __attribute__((ext_vector_type(4))) float floatx4;

// ---------- helpers ----------
__device__ __forceinline__ float siluf(float x) {
    float e = __expf(-fabsf(x));
    float s = (x >= 0.f) ? 1.f / (1.f + e) : e / (1.f + e);
    return x * s;
}
__device__ __forceinline__ float softplusf(float x) {
    if (x > 20.f) return x;
    if (x < -20.f) return __expf(x);
    return log1pf(__expf(x));
}
__device__ __forceinline__ unsigned short f2b(float v) {
    __hip_bfloat16 b = __float2bfloat16(v);
    unsigned short u;
    __builtin_memcpy(&u, &b, 2);
    return u;
}

// ---------- generic 64x64 tiled GEMM (fp32) — stage A + small stage-C ----------
template<bool ACOL, bool BCOL, bool AMUL, int EPI>
__global__ __launch_bounds__(256) void gemm64(
    const float* __restrict__ A, const float* __restrict__ Bw, float* __restrict__ C,
    const float* __restrict__ A2, const float* __restrict__ bias,
    int M, int N, int K, int lda, int ldb, int ldc, int lda2,
    long batA, long batB, long batC)
{
    __shared__ __align__(16) float As[16][64];
    __shared__ __align__(16) float Bs[16][64];
    int tx = threadIdx.x;
    int m0 = blockIdx.x * 64, n0 = blockIdx.y * 64;
    A += blockIdx.z * batA; Bw += blockIdx.z * batB; C += blockIdx.z * batC;
    int tm = tx >> 4, tn = tx & 15;
    float acc[4][4] = {};
    for (int k0 = 0; k0 < K; k0 += 16) {
        for (int i = tx; i < 1024; i += 256) {
            int mm, kk;
            if (ACOL) { mm = i & 63; kk = i >> 6; } else { kk = i & 15; mm = i >> 4; }
            int m = m0 + mm, k = k0 + kk;
            float v = 0.f;
            if (m < M && k < K) {
                long ia = ACOL ? ((long)k * lda + m) : ((long)m * lda + k);
                v = A[ia];
                if (AMUL) v *= siluf(A2[(long)m * lda2 + k]);
            }
            As[kk][mm] = v;
        }
        for (int i = tx; i < 1024; i += 256) {
            int nn, kk;
            if (BCOL) { kk = i & 15; nn = i >> 4; } else { nn = i & 63; kk = i >> 6; }
            int n = n0 + nn, k = k0 + kk;
            float v = 0.f;
            if (n < N && k < K) {
                long ib = BCOL ? ((long)n * ldb + k) : ((long)k * ldb + n);
                v = Bw[ib];
            }
            Bs[kk][nn] = v;
        }
        __syncthreads();
#pragma unroll
        for (int kk = 0; kk < 16; ++kk) {
            float4 av = *(const float4*)&As[kk][tm * 4];
            float4 bv = *(const float4*)&Bs[kk][tn * 4];
            float a[4] = {av.x, av.y, av.z, av.w};
            float b[4] = {bv.x, bv.y, bv.z, bv.w};
#pragma unroll
            for (int i = 0; i < 4; i++)
#pragma unroll
                for (int j = 0; j < 4; j++) acc[i][j] += a[i] * b[j];
        }
        __syncthreads();
    }
#pragma unroll
    for (int i = 0; i < 4; i++) {
        int m = m0 + tm * 4 + i;
        if (m >= M) continue;
#pragma unroll
        for (int j = 0; j < 4; j++) {
            int n = n0 + tn * 4 + j;
            if (n >= N) continue;
            float v = acc[i][j];
            if (EPI == 1) v = softplusf(v + bias[n]);
            C[(long)m * ldc + n] = v;
        }
    }
}

// ---------- bf16 MFMA GEMM: C[M,N] = A[M,K] x B[K,N] ----------
// Abf: bf16 bits, row-major [Mpad][K] (Mpad >= gridDim.x*128)
// Bbf: bf16 bits, B TRANSPOSED layout [N][K]
// 128x128 tile, 4 waves (2x2 of 64x64), 16x16x32 MFMA, BK=32.
__global__ __launch_bounds__(256) void mfma_gemm(
    const unsigned short* __restrict__ Abf, const unsigned short* __restrict__ Bbf,
    float* __restrict__ C, int M, int N, int K, int ldc)
{
    __shared__ __align__(16) short As[128 * 40];   // +8 pad kills ds_read conflicts
    __shared__ __align__(16) short Bs[128 * 40];
    int tid = threadIdx.x;
    int m0 = blockIdx.x * 128, n0 = blockIdx.y * 128;
    int w = tid >> 6, l = tid & 63;
    int wm = (w >> 1) * 64, wn = (w & 1) * 64;
    int lr = l & 15, lq = l >> 4;
    int row0 = tid >> 2, kc = (tid & 3) * 8;
    floatx4 acc[4][4];
#pragma unroll
    for (int i = 0; i < 4; i++)
#pragma unroll
        for (int j = 0; j < 4; j++) acc[i][j] = (floatx4){0.f, 0.f, 0.f, 0.f};
    const unsigned short* Ap  = Abf + (long)(m0 + row0) * K + kc;
    const unsigned short* Ap2 = Abf + (long)(m0 + row0 + 64) * K + kc;
    const unsigned short* Bp  = Bbf + (long)(n0 + row0) * K + kc;
    const unsigned short* Bp2 = Bbf + (long)(n0 + row0 + 64) * K + kc;
    for (int k0 = 0; k0 < K; k0 += 32) {
        uint4 a0 = *(const uint4*)(Ap + k0);
        uint4 a1 = *(const uint4*)(Ap2 + k0);
        uint4 b0 = *(const uint4*)(Bp + k0);
        uint4 b1 = *(const uint4*)(Bp2 + k0);
        __syncthreads();
        *(uint4*)&As[row0 * 40 + kc] = a0;
        *(uint4*)&As[(row0 + 64) * 40 + kc] = a1;
        *(uint4*)&Bs[row0 * 40 + kc] = b0;
        *(uint4*)&Bs[(row0 + 64) * 40 + kc] = b1;
        __syncthreads();
        short8 af[4], bfr[4];
#pragma unroll
        for (int i = 0; i < 4; i++) af[i]  = *(const short8*)&As[(wm + i * 16 + lr) * 40 + lq * 8];
#pragma unroll
        for (int i = 0; i < 4; i++) bfr[i] = *(const short8*)&Bs[(wn + i * 16 + lr) * 40 + lq * 8];
#pragma unroll
        for (int i = 0; i < 4; i++)
#pragma unroll
            for (int j = 0; j < 4; j++)
                acc[i][j] = __builtin_amdgcn_mfma_f32_16x16x32_bf16(af[i], bfr[j], acc[i][j], 0, 0, 0);
    }
#pragma unroll
    for (int i = 0; i < 4; i++) {
#pragma unroll
        for (int r = 0; r < 4; r++) {
            int m = m0 + wm + i * 16 + lq * 4 + r;
            if (m >= M) continue;
#pragma unroll
            for (int j = 0; j < 4; j++)
                C[(long)m * ldc + n0 + wn + j * 16 + lr] = acc[i][j][r];
        }
    }
}

// ---------- fp32 [K][N] -> bf16-bits transposed [N][K] (tiled via LDS) ----------
__global__ __launch_bounds__(256) void tpose_cvt(const float* __restrict__ src,
                                                 unsigned short* __restrict__ dst,
                                                 int K, int N)
{
    __shared__ float t[32][33];
    int n0 = blockIdx.x * 32, k0 = blockIdx.y * 32;
    int tid = threadIdx.x;
    int r = tid >> 3, c4 = (tid & 7) * 4;
    float4 v = *(const float4*)&src[(long)(k0 + r) * N + n0 + c4];
    t[r][c4] = v.x; t[r][c4 + 1] = v.y; t[r][c4 + 2] = v.z; t[r][c4 + 3] = v.w;
    __syncthreads();
    ushort4 o;
    o.x = f2b(t[c4][r]);
    o.y = f2b(t[c4 + 1][r]);
    o.z = f2b(t[c4 + 2][r]);
    o.w = f2b(t[c4 + 3][r]);
    *(ushort4*)&dst[(long)(n0 + r) * K + k0 + c4] = o;
}

// ---------- fp32 [M][C] -> bf16-bits [Mpad][C] (zero pad rows >= M) ----------
__global__ void cvt_pad(const float* __restrict__ src, unsigned short* __restrict__ dst,
                        int M, int Mpad, int C)
{
    long i4 = ((long)blockIdx.x * 256 + threadIdx.x) * 4;
    if (i4 >= (long)Mpad * C) return;
    int row = (int)(i4 / C);
    ushort4 o = {0, 0, 0, 0};
    if (row < M) {
        float4 v = *(const float4*)&src[i4];
        o.x = f2b(v.x); o.y = f2b(v.y); o.z = f2b(v.z); o.w = f2b(v.w);
    }
    *(ushort4*)&dst[i4] = o;
}

// ---------- y * silu(z) -> bf16-bits [Mpad][C] ----------
__global__ void gate_cvt(const float* __restrict__ y, const float* __restrict__ z,
                         unsigned short* __restrict__ dst, int M, int Mpad, int C, int ldz)
{
    long i4 = ((long)blockIdx.x * 256 + threadIdx.x) * 4;
    if (i4 >= (long)Mpad * C) return;
    int row = (int)(i4 / C);
    int col = (int)(i4 - (long)row * C);
    ushort4 o = {0, 0, 0, 0};
    if (row < M) {
        float4 yv = *(const float4*)&y[i4];
        float4 zv = *(const float4*)&z[(long)row * ldz + col];
        o.x = f2b(yv.x * siluf(zv.x));
        o.y = f2b(yv.y * siluf(zv.y));
        o.z = f2b(yv.z * siluf(zv.z));
        o.w = f2b(yv.w * siluf(zv.w));
    }
    *(ushort4*)&dst[i4] = o;
}

// ---------- causal depthwise conv (k=4) + bias + silu ----------
__global__ void conv_silu_kernel(const float* __restrict__ xz, const float* __restrict__ w,
                                 const float* __restrict__ bias, float* __restrict__ out,
                                 int Bn, int L, int din, int ldx)
{
    int idx = blockIdx.x * 256 + threadIdx.x;
    int total = Bn * L * din;
    if (idx >= total) return;
    int c = idx % din;
    int r = idx / din;
    int t = r % L;
    int b = r / L;
    float acc = bias[c];
#pragma unroll
    for (int i = 0; i < 4; i++) {
        int tt = t - 3 + i;
        if (tt >= 0) acc += w[c * 4 + i] * xz[((long)(b * L + tt)) * ldx + c];
    }
    out[idx] = siluf(acc);
}

// ---------- selective scan (u/y may alias) ----------
template<int T>
__global__ __launch_bounds__(256) void scan_kernel(
    const float* u, const float* dt,
    const float* xdbl, const float* __restrict__ A_log,
    const float* __restrict__ Dp, float* y,
    int din, int L, int xld, int boff, int coff)
{
    __shared__ float Bc[T][16], Cc[T][16], dtc[T][16], uc[T][16], yc[T][16];
    int tx = threadIdx.x;
    int dl = tx >> 4;
    int n = tx & 15;
    int dbase = blockIdx.x * 16;
    int dg = dbase + dl;
    int b = blockIdx.y;
    bool act = dg < din;
    float Acoef = act ? -__expf(A_log[dg * 16 + n]) : 0.f;
    float Dv = act ? Dp[dg] : 0.f;
    int nvalid = min(16, din - dbase);
    float h = 0.f;
    for (int c0 = 0; c0 < L; c0 += T) {
        int tcnt = min(T, L - c0);
        for (int i = tx; i < T * 16; i += 256) {
            int tt = i >> 4, c = i & 15;
            if (tt < tcnt) {
                long row = (long)b * L + c0 + tt;
                float uv = 0.f, dv = 0.f;
                if (c < nvalid) { uv = u[row * din + dbase + c]; dv = dt[row * din + dbase + c]; }
                uc[tt][c] = uv; dtc[tt][c] = dv;
                Bc[tt][c] = xdbl[row * xld + boff + c];
                Cc[tt][c] = xdbl[row * xld + coff + c];
            }
        }
        __syncthreads();
        for (int tt = 0; tt < tcnt; ++tt) {
            float dtv = dtc[tt][dl];
            float uv = uc[tt][dl];
            float dA = __expf(dtv * Acoef);
            h = dA * h + (dtv * uv) * Bc[tt][n];
            float p = h * Cc[tt][n];
            p += __shfl_xor(p, 1);
            p += __shfl_xor(p, 2);
            p += __shfl_xor(p, 4);
            p += __shfl_xor(p, 8);
            if (n == 0) yc[tt][dl] = p + Dv * uv;
        }
        __syncthreads();
        for (int i = tx; i < tcnt * 16; i += 256) {
            int tt = i >> 4, c = i & 15;
            if (c < nvalid) y[((long)b * L + c0 + tt) * din + dbase + c] = yc[tt][c];
        }
        __syncthreads();
    }
}

// ---------- mean over n (98) + softmax over k (1024), per batch ----------
__global__ void mean_softmax_kernel(const float* __restrict__ sc2, float* __restrict__ s)
{
    __shared__ float vals[1024];
    __shared__ float red[256];
    int b = blockIdx.x, tx = threadIdx.x;
    for (int k = tx; k < 1024; k += 256) {
        const float* row = sc2 + ((long)b * 1024 + k) * 98;
        float sum = 0.f;
        for (int nn = 0; nn < 98; nn++) sum += row[nn];
        vals[k] = sum * (1.f / 98.f);
    }
    __syncthreads();
    float mx = -1e30f;
    for (int k = tx; k < 1024; k += 256) mx = fmaxf(mx, vals[k]);
    red[tx] = mx; __syncthreads();
    for (int st = 128; st > 0; st >>= 1) { if (tx < st) red[tx] = fmaxf(red[tx], red[tx + st]); __syncthreads(); }
    mx = red[0]; __syncthreads();
    float lsum = 0.f;
    for (int k = tx; k < 1024; k += 256) { float e = __expf(vals[k] - mx); vals[k] = e; lsum += e; }
    red[tx] = lsum; __syncthreads();
    for (int st = 128; st > 0; st >>= 1) { if (tx < st) red[tx] += red[tx + st]; __syncthreads(); }
    float inv = 1.f / red[0];
    __syncthreads();
    for (int k = tx; k < 1024; k += 256) s[(long)b * 1024 + k] = vals[k] * inv;
}

// ---------- top-98 sequential selection (jax tie semantics) ----------
__global__ __launch_bounds__(256) void topk_select_kernel(const float* __restrict__ s,
                                                          int* __restrict__ ind,
                                                          float* __restrict__ vtopk)
{
    __shared__ unsigned long long arr[1024];
    __shared__ unsigned long long red[256];
    int b = blockIdx.x, tx = threadIdx.x;
    for (int k = tx; k < 1024; k += 256) {
        float v = s[b * 1024 + k];
        unsigned u = __float_as_uint(v);
        u = (u & 0x80000000u) ? ~u : (u | 0x80000000u);
        arr[k] = ((unsigned long long)u << 32) | (unsigned)(~k);
    }
    __syncthreads();
    for (int r = 0; r < 98; ++r) {
        unsigned long long m = 0ull;
        for (int k = tx; k < 1024; k += 256) m = (arr[k] > m) ? arr[k] : m;
        red[tx] = m; __syncthreads();
        for (int st = 128; st > 0; st >>= 1) {
            if (tx < st && red[tx + st] > red[tx]) red[tx] = red[tx + st];
            __syncthreads();
        }
        unsigned long long best = red[0];
        if (tx == 0) {
            unsigned lo = (unsigned)(best & 0xffffffffu);
            int kidx = (int)(~lo);
            unsigned ub = (unsigned)(best >> 32);
            unsigned fb = (ub & 0x80000000u) ? (ub ^ 0x80000000u) : ~ub;
            ind[b * 98 + r] = kidx;
            vtopk[b * 98 + r] = __uint_as_float(fb);
            arr[kidx] = 0ull;
        }
        __syncthreads();
    }
}

// ---------- gather: h[b,j,:] = img[j,:] + kf[b,:,ind]*v ----------
__global__ void gather_kernel(const float* __restrict__ img, const float* __restrict__ kf,
                              const int* __restrict__ ind, const float* __restrict__ vtopk,
                              float* __restrict__ h)
{
    int j = blockIdx.x, b = blockIdx.y;
    int kidx = ind[b * 98 + j];
    float v = vtopk[b * 98 + j];
    long hbase = ((long)b * 98 + j) * 2048;
    const float* kfb = kf + (long)b * 2048 * 1024 + kidx;
    for (int d = threadIdx.x; d < 2048; d += 256)
        h[hbase + d] = img[(long)j * 2048 + d] + kfb[(long)d * 1024] * v;
}

// ---------- host launch ----------
extern "C" void kernel_launch(void* const* d_in, const int* in_sizes, int n_in,
                              void* d_out, int out_size, void* d_ws, size_t ws_size,
                              hipStream_t stream)
{
    const float* imgF      = (const float*)d_in[0];
    const float* kf        = (const float*)d_in[1];
    const float* a_in_w    = (const float*)d_in[2];
    const float* a_conv_w  = (const float*)d_in[3];
    const float* a_conv_b  = (const float*)d_in[4];
    const float* a_xproj_w = (const float*)d_in[5];
    const float* a_dt_w    = (const float*)d_in[6];
    const float* a_dt_b    = (const float*)d_in[7];
    const float* a_A_log   = (const float*)d_in[8];
    const float* a_D       = (const float*)d_in[9];
    const float* a_out_w   = (const float*)d_in[10];
    const float* c_in_w    = (const float*)d_in[11];
    const float* c_conv_w  = (const float*)d_in[12];
    const float* c_conv_b  = (const float*)d_in[13];
    const float* c_xproj_w = (const float*)d_in[14];
    const float* c_dt_w    = (const float*)d_in[15];
    const float* c_dt_b    = (const float*)d_in[16];
    const float* c_A_log   = (const float*)d_in[17];
    const float* c_D       = (const float*)d_in[18];
    const float* c_out_w   = (const float*)d_in[19];

    float* fout = (float*)d_out;

    float* ws = (float*)d_ws;
    float* h_buf  = ws;                      // 1,605,632 floats
    float* S      = ws + 1605632;
    // stage A
    float* score  = S;                       // 802,816 (reused as score2)
    float* xz_a   = S + 802816;              // 3,211,264
    float* xi_a   = S + 4014080;             // 1,605,632 (scan in-place)
    float* xdbl_a = S + 5619712;             // 319,488
    float* dt_a   = S + 5939200;             // 1,605,632
    float* sbuf   = S + 7544832;             // 8,192
    int*   indb   = (int*)(S + 7553024);     // 784
    float* vtopk  = S + 7553808;             // 784
    // stage C (aliases stage A region)
    float* xz_c   = S;                       // 6,422,528
    float* xi_c   = S + 6422528;             // 3,211,264 (scan in-place)
    float* xdbl_c = S + 9633792;             // 125,440
    float* dt_c   = S + 9759232;             // 3,211,264
    // bf16 scratch (beyond the fp32 region: base float offset 14,576,128)
    unsigned short* cwbf  = (unsigned short*)(ws + 14576128);          // 16,777,216 bf16
    unsigned short* h_bf  = (unsigned short*)(ws + 14576128 + 8388608);// 1,835,008 bf16
    unsigned short* yz_bf = (unsigned short*)(ws + 14576128 + 9306112);// 3,670,016 bf16
    // total ws: 25,717,248 floats ~= 103 MB

    // ===== stage A (fp32, unchanged) =====
    gemm64<true, true, false, 0><<<dim3(16, 2, 8), 256, 0, stream>>>(
        kf, imgF, score, nullptr, nullptr,
        1024, 98, 2048, 1024, 2048, 98, 0,
        (long)2048 * 1024, 0L, (long)1024 * 98);
    gemm64<false, false, false, 0><<<dim3(128, 7, 1), 256, 0, stream>>>(
        score, a_in_w, xz_a, nullptr, nullptr, 8192, 392, 98, 98, 392, 392, 0, 0L, 0L, 0L);
    conv_silu_kernel<<<6272, 256, 0, stream>>>(xz_a, a_conv_w, a_conv_b, xi_a, 8, 1024, 196, 392);
    gemm64<false, false, false, 0><<<dim3(128, 1, 1), 256, 0, stream>>>(
        xi_a, a_xproj_w, xdbl_a, nullptr, nullptr, 8192, 39, 196, 196, 39, 39, 0, 0L, 0L, 0L);
    gemm64<false, false, false, 1><<<dim3(128, 4, 1), 256, 0, stream>>>(
        xdbl_a, a_dt_w, dt_a, nullptr, a_dt_b, 8192, 196, 7, 39, 196, 196, 0, 0L, 0L, 0L);
    scan_kernel<64><<<dim3(13, 8, 1), 256, 0, stream>>>(
        xi_a, dt_a, xdbl_a, a_A_log, a_D, xi_a, 196, 1024, 39, 7, 23);
    gemm64<false, false, true, 0><<<dim3(128, 2, 1), 256, 0, stream>>>(
        xi_a, a_out_w, score, xz_a + 196, nullptr, 8192, 98, 196, 196, 98, 98, 392, 0L, 0L, 0L);
    mean_softmax_kernel<<<8, 256, 0, stream>>>(score, sbuf);
    topk_select_kernel<<<8, 256, 0, stream>>>(sbuf, indb, vtopk);
    gather_kernel<<<dim3(98, 8, 1), 256, 0, stream>>>(imgF, kf, indb, vtopk, h_buf);

    // ===== stage C =====
    // 11. xz_c = h @ c_in_w  (bf16 MFMA)
    tpose_cvt<<<dim3(256, 64, 1), 256, 0, stream>>>(c_in_w, cwbf, 2048, 8192);
    cvt_pad<<<1792, 256, 0, stream>>>(h_buf, h_bf, 784, 896, 2048);
    mfma_gemm<<<dim3(7, 64, 1), 256, 0, stream>>>(h_bf, cwbf, xz_c, 784, 8192, 2048, 8192);

    // 12. conv + silu -> xi_c
    conv_silu_kernel<<<12544, 256, 0, stream>>>(xz_c, c_conv_w, c_conv_b, xi_c, 8, 98, 4096, 8192);

    // 13. xdbl_c = xi_c @ c_xproj_w (fp32)
    gemm64<false, false, false, 0><<<dim3(13, 3, 1), 256, 0, stream>>>(
        xi_c, c_xproj_w, xdbl_c, nullptr, nullptr, 784, 160, 4096, 4096, 160, 160, 0, 0L, 0L, 0L);

    // 14. dt_c = softplus(xdbl_c[:, :128] @ c_dt_w + c_dt_b) (fp32)
    gemm64<false, false, false, 1><<<dim3(13, 64, 1), 256, 0, stream>>>(
        xdbl_c, c_dt_w, dt_c, nullptr, c_dt_b, 784, 4096, 128, 160, 4096, 4096, 0, 0L, 0L, 0L);

    // 15. selective scan C (in-place)
    scan_kernel<98><<<dim3(256, 8, 1), 256, 0, stream>>>(
        xi_c, dt_c, xdbl_c, c_A_log, c_D, xi_c, 4096, 98, 160, 128, 144);

    // 16. out = (y_c * silu(z_c)) @ c_out_w  (bf16 MFMA, direct to d_out)
    gate_cvt<<<3584, 256, 0, stream>>>(xi_c, xz_c + 4096, yz_bf, 784, 896, 4096, 8192);
    tpose_cvt<<<dim3(64, 128, 1), 256, 0, stream>>>(c_out_w, cwbf, 4096, 2048);
    mfma_gemm<<<dim3(7, 16, 1), 256, 0, stream>>>(yz_bf, cwbf, fout, 784, 2048, 4096, 2048);
}